// Round 1
// baseline (288.226 us; speedup 1.0000x reference)
//
#include <hip/hip_runtime.h>

// Problem constants (from reference)
constexpr int NN = 50000;   // nodes
constexpr int NE = 800000;  // edges
constexpr int FN = 64;      // node feat
constexpr int FE = 32;      // edge feat
constexpr int FG = 32;      // global feat
constexpr int OD = 64;      // out dim
constexpr int NG = 256;     // graphs

// ---------------------------------------------------------------------------
// Kernel 1: xW1[n][j] = b1[j] + sum_k x[n][k] * W1[k][j]   (rows 0..63 of W1)
// One wave per node row. Row index made wave-uniform -> x row loads scalarize
// (s_load), W column lives in 64 VGPRs per lane, inner loop = 64 v_fmac.
// ---------------------------------------------------------------------------
__global__ __launch_bounds__(256) void k_xw1(const float* __restrict__ x,
                                             const float* __restrict__ W1,
                                             const float* __restrict__ b1,
                                             float* __restrict__ xW1) {
    const int lane = threadIdx.x & 63;
    float wcol[FN];
#pragma unroll
    for (int k = 0; k < FN; ++k) wcol[k] = W1[k * OD + lane];
    const float bias = b1[lane];

    const int wavesTotal = (gridDim.x * blockDim.x) >> 6;
    int w = (blockIdx.x * blockDim.x + threadIdx.x) >> 6;
    w = __builtin_amdgcn_readfirstlane(w);

    for (int n = w; n < NN; n += wavesTotal) {
        const float* __restrict__ xrow = x + (size_t)n * FN;
        float acc = bias;
#pragma unroll
        for (int k = 0; k < FN; ++k) acc = fmaf(xrow[k], wcol[k], acc);
        xW1[(size_t)n * OD + lane] = acc;
    }
}

// ---------------------------------------------------------------------------
// Kernel 2: uW2b[g][j] = b2[j] + sum_k u[g][k] * W2[(128+k)][j]
// One wave per graph (256 graphs).
// ---------------------------------------------------------------------------
__global__ __launch_bounds__(256) void k_uw2(const float* __restrict__ u,
                                             const float* __restrict__ W2,
                                             const float* __restrict__ b2,
                                             float* __restrict__ uW2b) {
    const int lane = threadIdx.x & 63;
    float wcol[FG];
#pragma unroll
    for (int k = 0; k < FG; ++k) wcol[k] = W2[(FN + OD + k) * OD + lane];
    const float bias = b2[lane];

    int w = (blockIdx.x * blockDim.x + threadIdx.x) >> 6;
    w = __builtin_amdgcn_readfirstlane(w);
    if (w < NG) {
        const float* __restrict__ urow = u + (size_t)w * FG;
        float acc = bias;
#pragma unroll
        for (int k = 0; k < FG; ++k) acc = fmaf(urow[k], wcol[k], acc);
        uW2b[(size_t)w * OD + lane] = acc;
    }
}

// ---------------------------------------------------------------------------
// Kernel 3 (edge pass): for each edge e:
//   msg[j] = relu( xW1[src][j] + sum_k ea[e][k] * W1[(64+k)][j] )
//   atomicAdd(agg[dst][j], msg[j])
// One wave per edge (looped over a contiguous chunk). e is wave-uniform ->
// dst/src/ea loads scalarize; per-lane work = 32 v_fmac + 1 gather + 1 atomic.
// ---------------------------------------------------------------------------
__global__ __launch_bounds__(256) void k_edge(const int* __restrict__ ei,
                                              const float* __restrict__ ea,
                                              const float* __restrict__ xW1,
                                              const float* __restrict__ W1,
                                              float* __restrict__ agg) {
    const int lane = threadIdx.x & 63;
    float wcol[FE];
#pragma unroll
    for (int k = 0; k < FE; ++k) wcol[k] = W1[(FN + k) * OD + lane];

    const int wavesTotal = (gridDim.x * blockDim.x) >> 6;
    int w = (blockIdx.x * blockDim.x + threadIdx.x) >> 6;
    w = __builtin_amdgcn_readfirstlane(w);

    const int chunk = (NE + wavesTotal - 1) / wavesTotal;
    const int e0 = w * chunk;
    const int e1 = (e0 + chunk < NE) ? (e0 + chunk) : NE;

    for (int e = e0; e < e1; ++e) {
        const int dst = ei[e];        // edge_index[0][e]
        const int src = ei[NE + e];   // edge_index[1][e]
        float acc = xW1[(size_t)src * OD + lane];
        const float* __restrict__ earow = ea + (size_t)e * FE;
#pragma unroll
        for (int k = 0; k < FE; ++k) acc = fmaf(earow[k], wcol[k], acc);
        acc = fmaxf(acc, 0.0f);
        __hip_atomic_fetch_add(&agg[(size_t)dst * OD + lane], acc,
                               __ATOMIC_RELAXED, __HIP_MEMORY_SCOPE_AGENT);
    }
}

// ---------------------------------------------------------------------------
// Kernel 4 (node pass):
//   out[n][j] = relu( sum_k x[n][k]*W2[k][j] + sum_k agg[n][k]*W2[64+k][j]
//                     + uW2b[batch[n]][j] )
// One wave per node. 128 v_fmac per lane per node; x/agg rows scalarize.
// ---------------------------------------------------------------------------
__global__ __launch_bounds__(256) void k_node(const float* __restrict__ x,
                                              const float* __restrict__ agg,
                                              const int* __restrict__ batch,
                                              const float* __restrict__ uW2b,
                                              const float* __restrict__ W2,
                                              float* __restrict__ out) {
    const int lane = threadIdx.x & 63;
    float wx[FN];
    float wa[OD];
#pragma unroll
    for (int k = 0; k < FN; ++k) wx[k] = W2[k * OD + lane];
#pragma unroll
    for (int k = 0; k < OD; ++k) wa[k] = W2[(FN + k) * OD + lane];

    const int wavesTotal = (gridDim.x * blockDim.x) >> 6;
    int w = (blockIdx.x * blockDim.x + threadIdx.x) >> 6;
    w = __builtin_amdgcn_readfirstlane(w);

    for (int n = w; n < NN; n += wavesTotal) {
        const int g = batch[n];
        float acc = uW2b[(size_t)g * OD + lane];
        const float* __restrict__ xrow = x + (size_t)n * FN;
        const float* __restrict__ arow = agg + (size_t)n * OD;
#pragma unroll
        for (int k = 0; k < FN; ++k) acc = fmaf(xrow[k], wx[k], acc);
#pragma unroll
        for (int k = 0; k < OD; ++k) acc = fmaf(arow[k], wa[k], acc);
        out[(size_t)n * OD + lane] = fmaxf(acc, 0.0f);
    }
}

// ---------------------------------------------------------------------------
extern "C" void kernel_launch(void* const* d_in, const int* in_sizes, int n_in,
                              void* d_out, int out_size, void* d_ws, size_t ws_size,
                              hipStream_t stream) {
    const float* x    = (const float*)d_in[0];   // (50000, 64)
    const int*   ei   = (const int*)d_in[1];     // (2, 800000)
    const float* ea   = (const float*)d_in[2];   // (800000, 32)
    const float* u    = (const float*)d_in[3];   // (256, 32)
    const int*   bat  = (const int*)d_in[4];     // (50000,)
    const float* W1   = (const float*)d_in[5];   // (96, 64)
    const float* b1   = (const float*)d_in[6];   // (64,)
    const float* W2   = (const float*)d_in[7];   // (160, 64)
    const float* b2   = (const float*)d_in[8];   // (64,)
    float* out = (float*)d_out;                  // (50000, 64)

    // workspace layout (floats)
    float* ws   = (float*)d_ws;
    float* xW1  = ws;                          // 50000*64
    float* agg  = xW1 + (size_t)NN * OD;       // 50000*64
    float* uW2b = agg + (size_t)NN * OD;       // 256*64

    // zero the aggregation buffer (atomically accumulated each call)
    hipMemsetAsync(agg, 0, (size_t)NN * OD * sizeof(float), stream);

    // precomputes
    k_xw1<<<dim3(1024), dim3(256), 0, stream>>>(x, W1, b1, xW1);
    k_uw2<<<dim3(64), dim3(256), 0, stream>>>(u, W2, b2, uW2b);

    // edge pass
    k_edge<<<dim3(2048), dim3(256), 0, stream>>>(ei, ea, xW1, W1, agg);

    // node pass
    k_node<<<dim3(1024), dim3(256), 0, stream>>>(x, agg, bat, uW2b, W2, out);
}

// Round 2
// 261.922 us; speedup vs baseline: 1.1004x; 1.1004x over previous
//
#include <hip/hip_runtime.h>

// Problem constants (from reference)
constexpr int NN = 50000;   // nodes
constexpr int NE = 800000;  // edges
constexpr int FN = 64;      // node feat
constexpr int FE = 32;      // edge feat
constexpr int FG = 32;      // global feat
constexpr int OD = 64;      // out dim
constexpr int NG = 256;     // graphs

constexpr int SCAN_B = 256;
constexpr int NBLK = (NN + SCAN_B - 1) / SCAN_B;  // 196

// ---------------------------------------------------------------------------
// Kernel 1: xW1[n][j] = b1[j] + sum_k x[n][k] * W1[k][j]   (rows 0..63 of W1)
// One wave per node. Wave-uniform row -> x row scalarizes; W col in VGPRs.
// ---------------------------------------------------------------------------
__global__ __launch_bounds__(256) void k_xw1(const float* __restrict__ x,
                                             const float* __restrict__ W1,
                                             const float* __restrict__ b1,
                                             float* __restrict__ xW1) {
    const int lane = threadIdx.x & 63;
    float wcol[FN];
#pragma unroll
    for (int k = 0; k < FN; ++k) wcol[k] = W1[k * OD + lane];
    const float bias = b1[lane];

    int n = (blockIdx.x * blockDim.x + threadIdx.x) >> 6;
    n = __builtin_amdgcn_readfirstlane(n);
    if (n >= NN) return;

    const float* __restrict__ xrow = x + (size_t)n * FN;
    float acc = bias;
#pragma unroll
    for (int k = 0; k < FN; ++k) acc = fmaf(xrow[k], wcol[k], acc);
    xW1[(size_t)n * OD + lane] = acc;
}

// ---------------------------------------------------------------------------
// Kernel 2: uW2b[g][j] = b2[j] + sum_k u[g][k] * W2[(128+k)][j]
// ---------------------------------------------------------------------------
__global__ __launch_bounds__(256) void k_uw2(const float* __restrict__ u,
                                             const float* __restrict__ W2,
                                             const float* __restrict__ b2,
                                             float* __restrict__ uW2b) {
    const int lane = threadIdx.x & 63;
    float wcol[FG];
#pragma unroll
    for (int k = 0; k < FG; ++k) wcol[k] = W2[(FN + OD + k) * OD + lane];
    const float bias = b2[lane];

    int g = (blockIdx.x * blockDim.x + threadIdx.x) >> 6;
    g = __builtin_amdgcn_readfirstlane(g);
    if (g >= NG) return;

    const float* __restrict__ urow = u + (size_t)g * FG;
    float acc = bias;
#pragma unroll
    for (int k = 0; k < FG; ++k) acc = fmaf(urow[k], wcol[k], acc);
    uW2b[(size_t)g * OD + lane] = acc;
}

// ---------------------------------------------------------------------------
// Bucketing: histogram of dst (int atomics), 3-step scan, scatter {src,e}.
// ---------------------------------------------------------------------------
__global__ __launch_bounds__(256) void k_hist(const int* __restrict__ ei,
                                              int* __restrict__ cnt) {
    const int e = blockIdx.x * blockDim.x + threadIdx.x;
    if (e < NE) atomicAdd(&cnt[ei[e]], 1);
}

__global__ __launch_bounds__(SCAN_B) void k_scan1(const int* __restrict__ cnt,
                                                  int* __restrict__ start,
                                                  int* __restrict__ bsum) {
    __shared__ int lds[SCAN_B];
    const int i = blockIdx.x * SCAN_B + threadIdx.x;
    const int v = (i < NN) ? cnt[i] : 0;
    lds[threadIdx.x] = v;
    __syncthreads();
#pragma unroll
    for (int off = 1; off < SCAN_B; off <<= 1) {
        int t = (threadIdx.x >= off) ? lds[threadIdx.x - off] : 0;
        __syncthreads();
        lds[threadIdx.x] += t;
        __syncthreads();
    }
    const int incl = lds[threadIdx.x];
    if (i < NN) start[i] = incl - v;  // exclusive within block
    if (threadIdx.x == SCAN_B - 1) bsum[blockIdx.x] = incl;
}

__global__ __launch_bounds__(SCAN_B) void k_scan2(const int* __restrict__ bsum,
                                                  int* __restrict__ bscan) {
    __shared__ int lds[SCAN_B];
    const int i = threadIdx.x;
    const int v = (i < NBLK) ? bsum[i] : 0;
    lds[i] = v;
    __syncthreads();
#pragma unroll
    for (int off = 1; off < SCAN_B; off <<= 1) {
        int t = (i >= off) ? lds[i - off] : 0;
        __syncthreads();
        lds[i] += t;
        __syncthreads();
    }
    if (i < NBLK) bscan[i] = lds[i] - v;  // exclusive block offsets
}

__global__ __launch_bounds__(SCAN_B) void k_scan3(int* __restrict__ start,
                                                  const int* __restrict__ bscan,
                                                  int* __restrict__ cursor) {
    const int i = blockIdx.x * SCAN_B + threadIdx.x;
    if (i < NN) {
        const int s = start[i] + bscan[blockIdx.x];
        start[i] = s;
        cursor[i] = s;
    }
    if (i == 0) start[NN] = NE;
}

__global__ __launch_bounds__(256) void k_scatter(const int* __restrict__ ei,
                                                 int* __restrict__ cursor,
                                                 int2* __restrict__ bucket) {
    const int e = blockIdx.x * blockDim.x + threadIdx.x;
    if (e < NE) {
        const int dst = ei[e];
        const int src = ei[NE + e];
        const int pos = atomicAdd(&cursor[dst], 1);
        bucket[pos] = make_int2(src, e);
    }
}

// ---------------------------------------------------------------------------
// Kernel 3 (aggregation): one wave per node. Walk the node's edge bucket,
// recompute each message msg = relu(xW1[src] + ea[e] @ W1_bot), accumulate in
// registers, store agg[n] once. No float atomics anywhere.
// Unrolled by 2 for two independent scalar-load/FMA streams.
// ---------------------------------------------------------------------------
__global__ __launch_bounds__(256) void k_agg(const int2* __restrict__ bucket,
                                             const float* __restrict__ ea,
                                             const float* __restrict__ xW1,
                                             const float* __restrict__ W1,
                                             const int* __restrict__ start,
                                             float* __restrict__ agg) {
    const int lane = threadIdx.x & 63;
    float wcol[FE];
#pragma unroll
    for (int k = 0; k < FE; ++k) wcol[k] = W1[(FN + k) * OD + lane];

    int n = (blockIdx.x * blockDim.x + threadIdx.x) >> 6;
    n = __builtin_amdgcn_readfirstlane(n);
    if (n >= NN) return;

    const int s0 = start[n];
    const int s1 = start[n + 1];
    float acc = 0.0f;
    int i = s0;
    for (; i + 1 < s1; i += 2) {
        const int2 p0 = bucket[i];
        const int2 p1 = bucket[i + 1];
        const float* __restrict__ ea0 = ea + (size_t)p0.y * FE;
        const float* __restrict__ ea1 = ea + (size_t)p1.y * FE;
        float m0 = xW1[(size_t)p0.x * OD + lane];
        float m1 = xW1[(size_t)p1.x * OD + lane];
#pragma unroll
        for (int k = 0; k < FE; ++k) m0 = fmaf(ea0[k], wcol[k], m0);
#pragma unroll
        for (int k = 0; k < FE; ++k) m1 = fmaf(ea1[k], wcol[k], m1);
        acc += fmaxf(m0, 0.0f) + fmaxf(m1, 0.0f);
    }
    if (i < s1) {
        const int2 p0 = bucket[i];
        const float* __restrict__ ea0 = ea + (size_t)p0.y * FE;
        float m0 = xW1[(size_t)p0.x * OD + lane];
#pragma unroll
        for (int k = 0; k < FE; ++k) m0 = fmaf(ea0[k], wcol[k], m0);
        acc += fmaxf(m0, 0.0f);
    }
    agg[(size_t)n * OD + lane] = acc;
}

// ---------------------------------------------------------------------------
// Kernel 4 (node pass): out = relu(x@W2x + agg@W2agg + uW2b[batch])
// ---------------------------------------------------------------------------
__global__ __launch_bounds__(256) void k_node(const float* __restrict__ x,
                                              const float* __restrict__ agg,
                                              const int* __restrict__ batch,
                                              const float* __restrict__ uW2b,
                                              const float* __restrict__ W2,
                                              float* __restrict__ out) {
    const int lane = threadIdx.x & 63;
    float wx[FN];
    float wa[OD];
#pragma unroll
    for (int k = 0; k < FN; ++k) wx[k] = W2[k * OD + lane];
#pragma unroll
    for (int k = 0; k < OD; ++k) wa[k] = W2[(FN + k) * OD + lane];

    int n = (blockIdx.x * blockDim.x + threadIdx.x) >> 6;
    n = __builtin_amdgcn_readfirstlane(n);
    if (n >= NN) return;

    const int g = batch[n];
    float acc = uW2b[(size_t)g * OD + lane];
    const float* __restrict__ xrow = x + (size_t)n * FN;
    const float* __restrict__ arow = agg + (size_t)n * OD;
#pragma unroll
    for (int k = 0; k < FN; ++k) acc = fmaf(xrow[k], wx[k], acc);
#pragma unroll
    for (int k = 0; k < OD; ++k) acc = fmaf(arow[k], wa[k], acc);
    out[(size_t)n * OD + lane] = fmaxf(acc, 0.0f);
}

// ---------------------------------------------------------------------------
extern "C" void kernel_launch(void* const* d_in, const int* in_sizes, int n_in,
                              void* d_out, int out_size, void* d_ws, size_t ws_size,
                              hipStream_t stream) {
    const float* x    = (const float*)d_in[0];   // (50000, 64)
    const int*   ei   = (const int*)d_in[1];     // (2, 800000)
    const float* ea   = (const float*)d_in[2];   // (800000, 32)
    const float* u    = (const float*)d_in[3];   // (256, 32)
    const int*   bat  = (const int*)d_in[4];     // (50000,)
    const float* W1   = (const float*)d_in[5];   // (96, 64)
    const float* b1   = (const float*)d_in[6];   // (64,)
    const float* W2   = (const float*)d_in[7];   // (160, 64)
    const float* b2   = (const float*)d_in[8];   // (64,)
    float* out = (float*)d_out;                  // (50000, 64)

    // workspace layout
    char* ws = (char*)d_ws;
    auto alloc = [&](size_t bytes) {
        char* p = ws;
        ws += (bytes + 255) & ~size_t(255);
        return p;
    };
    float* xW1    = (float*)alloc((size_t)NN * OD * sizeof(float));   // 12.8 MB
    float* agg    = (float*)alloc((size_t)NN * OD * sizeof(float));   // 12.8 MB
    float* uW2b   = (float*)alloc((size_t)NG * OD * sizeof(float));
    int*   cnt    = (int*)alloc((size_t)NN * sizeof(int));
    int*   start  = (int*)alloc((size_t)(NN + 1) * sizeof(int));
    int*   cursor = (int*)alloc((size_t)NN * sizeof(int));
    int*   bsum   = (int*)alloc((size_t)NBLK * sizeof(int));
    int*   bscan  = (int*)alloc((size_t)NBLK * sizeof(int));
    int2*  bucket = (int2*)alloc((size_t)NE * sizeof(int2));          // 6.4 MB

    // zero histogram (rebuilt deterministically every call)
    hipMemsetAsync(cnt, 0, (size_t)NN * sizeof(int), stream);

    // precomputes (independent of bucketing)
    k_xw1<<<dim3((NN * 64 + 255) / 256), dim3(256), 0, stream>>>(x, W1, b1, xW1);
    k_uw2<<<dim3((NG * 64 + 255) / 256), dim3(256), 0, stream>>>(u, W2, b2, uW2b);

    // bucket edges by destination
    k_hist<<<dim3((NE + 255) / 256), dim3(256), 0, stream>>>(ei, cnt);
    k_scan1<<<dim3(NBLK), dim3(SCAN_B), 0, stream>>>(cnt, start, bsum);
    k_scan2<<<dim3(1), dim3(SCAN_B), 0, stream>>>(bsum, bscan);
    k_scan3<<<dim3(NBLK), dim3(SCAN_B), 0, stream>>>(start, bscan, cursor);
    k_scatter<<<dim3((NE + 255) / 256), dim3(256), 0, stream>>>(ei, cursor, bucket);

    // aggregate (atomic-free)
    k_agg<<<dim3((NN * 64 + 255) / 256), dim3(256), 0, stream>>>(bucket, ea, xW1, W1, start, agg);

    // node MLP
    k_node<<<dim3((NN * 64 + 255) / 256), dim3(256), 0, stream>>>(x, agg, bat, uW2b, W2, out);
}

// Round 3
// 241.760 us; speedup vs baseline: 1.1922x; 1.0834x over previous
//
#include <hip/hip_runtime.h>
#include <hip/hip_bf16.h>

typedef __attribute__((ext_vector_type(8))) short short8;
typedef __attribute__((ext_vector_type(4))) float f32x4;

// Problem constants (from reference)
constexpr int NN = 50000;   // nodes
constexpr int NE = 800000;  // edges
constexpr int FN = 64;      // node feat
constexpr int FE = 32;      // edge feat
constexpr int FG = 32;      // global feat
constexpr int OD = 64;      // out dim
constexpr int NG = 256;     // graphs

constexpr int SCAN_B = 256;
constexpr int NBLK = (NN + SCAN_B - 1) / SCAN_B;  // 196

static __device__ __forceinline__ unsigned pack_bf16(float a, float b) {
    __hip_bfloat162 h = __float22bfloat162_rn(float2{a, b});
    return *reinterpret_cast<unsigned*>(&h);
}

// ---------------------------------------------------------------------------
// x (f32) -> x_bf16 table (50000 x 64), 8 elems per thread
// ---------------------------------------------------------------------------
__global__ __launch_bounds__(256) void k_xcvt(const float* __restrict__ x,
                                              unsigned* __restrict__ xb32) {
    const int i = blockIdx.x * 256 + threadIdx.x;  // per 8 elements
    if (i >= NN * FN / 8) return;
    const float4* p = (const float4*)(x + (size_t)i * 8);
    float4 f0 = p[0], f1 = p[1];
    uint4 o;
    o.x = pack_bf16(f0.x, f0.y);
    o.y = pack_bf16(f0.z, f0.w);
    o.z = pack_bf16(f1.x, f1.y);
    o.w = pack_bf16(f1.z, f1.w);
    ((uint4*)xb32)[i] = o;
}

// ---------------------------------------------------------------------------
// uW2b[g][j] = b2[j] + sum_k u[g][k] * W2[(128+k)][j]
// ---------------------------------------------------------------------------
__global__ __launch_bounds__(256) void k_uw2(const float* __restrict__ u,
                                             const float* __restrict__ W2,
                                             const float* __restrict__ b2,
                                             float* __restrict__ uW2b) {
    const int lane = threadIdx.x & 63;
    float wcol[FG];
#pragma unroll
    for (int k = 0; k < FG; ++k) wcol[k] = W2[(FN + OD + k) * OD + lane];
    const float bias = b2[lane];

    int g = (blockIdx.x * blockDim.x + threadIdx.x) >> 6;
    g = __builtin_amdgcn_readfirstlane(g);
    if (g >= NG) return;

    const float* __restrict__ urow = u + (size_t)g * FG;
    float acc = bias;
#pragma unroll
    for (int k = 0; k < FG; ++k) acc = fmaf(urow[k], wcol[k], acc);
    uW2b[(size_t)g * OD + lane] = acc;
}

// ---------------------------------------------------------------------------
// Bucketing: histogram of dst (int atomics), 3-step scan, scatter {src,e}.
// ---------------------------------------------------------------------------
__global__ __launch_bounds__(256) void k_hist(const int* __restrict__ ei,
                                              int* __restrict__ cnt) {
    const int e = blockIdx.x * blockDim.x + threadIdx.x;
    if (e < NE) atomicAdd(&cnt[ei[e]], 1);
}

__global__ __launch_bounds__(SCAN_B) void k_scan1(const int* __restrict__ cnt,
                                                  int* __restrict__ start,
                                                  int* __restrict__ bsum) {
    __shared__ int lds[SCAN_B];
    const int i = blockIdx.x * SCAN_B + threadIdx.x;
    const int v = (i < NN) ? cnt[i] : 0;
    lds[threadIdx.x] = v;
    __syncthreads();
#pragma unroll
    for (int off = 1; off < SCAN_B; off <<= 1) {
        int t = (threadIdx.x >= off) ? lds[threadIdx.x - off] : 0;
        __syncthreads();
        lds[threadIdx.x] += t;
        __syncthreads();
    }
    const int incl = lds[threadIdx.x];
    if (i < NN) start[i] = incl - v;  // exclusive within block
    if (threadIdx.x == SCAN_B - 1) bsum[blockIdx.x] = incl;
}

__global__ __launch_bounds__(SCAN_B) void k_scan2(const int* __restrict__ bsum,
                                                  int* __restrict__ bscan) {
    __shared__ int lds[SCAN_B];
    const int i = threadIdx.x;
    const int v = (i < NBLK) ? bsum[i] : 0;
    lds[i] = v;
    __syncthreads();
#pragma unroll
    for (int off = 1; off < SCAN_B; off <<= 1) {
        int t = (i >= off) ? lds[i - off] : 0;
        __syncthreads();
        lds[i] += t;
        __syncthreads();
    }
    if (i < NBLK) bscan[i] = lds[i] - v;  // exclusive block offsets
}

__global__ __launch_bounds__(SCAN_B) void k_scan3(int* __restrict__ start,
                                                  const int* __restrict__ bscan,
                                                  int* __restrict__ cursor) {
    const int i = blockIdx.x * SCAN_B + threadIdx.x;
    if (i < NN) {
        const int s = start[i] + bscan[blockIdx.x];
        start[i] = s;
        cursor[i] = s;
    }
    if (i == 0) start[NN] = NE;
}

__global__ __launch_bounds__(256) void k_scatter(const int* __restrict__ ei,
                                                 int* __restrict__ cursor,
                                                 int2* __restrict__ bucket) {
    const int e = blockIdx.x * blockDim.x + threadIdx.x;
    if (e < NE) {
        const int dst = ei[e];
        const int src = ei[NE + e];
        const int pos = atomicAdd(&cursor[dst], 1);
        bucket[pos] = make_int2(src, e);
    }
}

// ---------------------------------------------------------------------------
// Aggregation via MFMA. One wave per node; windows of 16 edges.
//   msg[r][j] = relu( [x_bf16[src_r] | ea_r] @ W1 + b1 ),  r = edge in window
//   agg[n][j] = sum over windows, rows masked to valid count.
// Fragment layouts (mfma_f32_16x16x32_bf16):
//   A: row = lane&15, k = 8*(lane>>4)+i   (8 bf16 / lane)
//   B: col = lane&15, k = 8*(lane>>4)+i
//   C: col = lane&15, row = (lane>>4)*4 + q   [measured m89]
// ---------------------------------------------------------------------------
__global__ __launch_bounds__(256) void k_aggm(const int2* __restrict__ bucket,
                                              const float* __restrict__ ea,
                                              const unsigned short* __restrict__ xb,
                                              const float* __restrict__ W1,
                                              const float* __restrict__ b1,
                                              const int* __restrict__ start,
                                              float* __restrict__ agg) {
    const int l = threadIdx.x & 63;
    const int g = l >> 4;   // k-group (A/B), row-group (C)
    const int c = l & 15;   // A row / B,C col-in-block

    // Build W1 B-fragments: wf[t][b] covers k = 32t.., cols 16b..16b+15
    short8 wf[3][4];
#pragma unroll
    for (int t = 0; t < 3; ++t)
#pragma unroll
        for (int b = 0; b < 4; ++b)
#pragma unroll
            for (int i = 0; i < 8; i += 2) {
                const int k = 32 * t + 8 * g + i;
                const unsigned p = pack_bf16(W1[k * OD + (c + 16 * b)],
                                             W1[(k + 1) * OD + (c + 16 * b)]);
                ((unsigned*)&wf[t][b])[i / 2] = p;
            }
    float bias[4];
#pragma unroll
    for (int b = 0; b < 4; ++b) bias[b] = b1[c + 16 * b];

    int n = (blockIdx.x * blockDim.x + threadIdx.x) >> 6;
    n = __builtin_amdgcn_readfirstlane(n);
    if (n >= NN) return;

    const int s0 = start[n];
    const int s1 = start[n + 1];

    f32x4 wsum[4] = {f32x4{0,0,0,0}, f32x4{0,0,0,0}, f32x4{0,0,0,0}, f32x4{0,0,0,0}};

    for (int w0 = s0; w0 < s1; w0 += 16) {
        const int valid = s1 - w0;  // rows >= valid are clamped duplicates
        int idx = w0 + c;
        if (idx >= s1) idx = s1 - 1;
        const int2 se = bucket[idx];  // {src, e}

        // A fragments: chunks 0,1 = x_bf16[src], chunk 2 = cvt(ea[e])
        short8 a0, a1, a2;
        {
            const uint4* xr = (const uint4*)(xb + (size_t)se.x * FN);
            uint4 q0 = xr[g];      // k = 8g..8g+7
            uint4 q1 = xr[4 + g];  // k = 64+8g..
            a0 = *(short8*)&q0;
            a1 = *(short8*)&q1;
        }
        {
            const float4* er = (const float4*)(ea + (size_t)se.y * FE);
            float4 e0 = er[2 * g], e1 = er[2 * g + 1];
            uint4 q2;
            q2.x = pack_bf16(e0.x, e0.y);
            q2.y = pack_bf16(e0.z, e0.w);
            q2.z = pack_bf16(e1.x, e1.y);
            q2.w = pack_bf16(e1.z, e1.w);
            a2 = *(short8*)&q2;
        }

#pragma unroll
        for (int b = 0; b < 4; ++b) {
            f32x4 acc = {0.f, 0.f, 0.f, 0.f};
            acc = __builtin_amdgcn_mfma_f32_16x16x32_bf16(a0, wf[0][b], acc, 0, 0, 0);
            acc = __builtin_amdgcn_mfma_f32_16x16x32_bf16(a1, wf[1][b], acc, 0, 0, 0);
            acc = __builtin_amdgcn_mfma_f32_16x16x32_bf16(a2, wf[2][b], acc, 0, 0, 0);
#pragma unroll
            for (int q = 0; q < 4; ++q) {
                const int row = g * 4 + q;
                float v = fmaxf(acc[q] + bias[b], 0.0f);
                wsum[b][q] += (row < valid) ? v : 0.0f;
            }
        }
    }

    // reduce rows: in-lane over q, cross-lane over row-groups (lanes ^16, ^32)
    float wsb0, wsb1, wsb2, wsb3;
    {
        float s0v = wsum[0][0] + wsum[0][1] + wsum[0][2] + wsum[0][3];
        float s1v = wsum[1][0] + wsum[1][1] + wsum[1][2] + wsum[1][3];
        float s2v = wsum[2][0] + wsum[2][1] + wsum[2][2] + wsum[2][3];
        float s3v = wsum[3][0] + wsum[3][1] + wsum[3][2] + wsum[3][3];
        s0v += __shfl_xor(s0v, 16); s0v += __shfl_xor(s0v, 32);
        s1v += __shfl_xor(s1v, 16); s1v += __shfl_xor(s1v, 32);
        s2v += __shfl_xor(s2v, 16); s2v += __shfl_xor(s2v, 32);
        s3v += __shfl_xor(s3v, 16); s3v += __shfl_xor(s3v, 32);
        wsb0 = s0v; wsb1 = s1v; wsb2 = s2v; wsb3 = s3v;
    }
    float v = wsb0;
    v = (g == 1) ? wsb1 : v;
    v = (g == 2) ? wsb2 : v;
    v = (g == 3) ? wsb3 : v;
    agg[(size_t)n * OD + c + 16 * g] = v;
}

// ---------------------------------------------------------------------------
// Node pass: out = relu(x@W2x + agg@W2agg + uW2b[batch])  (f32)
// ---------------------------------------------------------------------------
__global__ __launch_bounds__(256) void k_node(const float* __restrict__ x,
                                              const float* __restrict__ agg,
                                              const int* __restrict__ batch,
                                              const float* __restrict__ uW2b,
                                              const float* __restrict__ W2,
                                              float* __restrict__ out) {
    const int lane = threadIdx.x & 63;
    float wx[FN];
    float wa[OD];
#pragma unroll
    for (int k = 0; k < FN; ++k) wx[k] = W2[k * OD + lane];
#pragma unroll
    for (int k = 0; k < OD; ++k) wa[k] = W2[(FN + k) * OD + lane];

    int n = (blockIdx.x * blockDim.x + threadIdx.x) >> 6;
    n = __builtin_amdgcn_readfirstlane(n);
    if (n >= NN) return;

    const int gph = batch[n];
    float acc = uW2b[(size_t)gph * OD + lane];
    const float* __restrict__ xrow = x + (size_t)n * FN;
    const float* __restrict__ arow = agg + (size_t)n * OD;
#pragma unroll
    for (int k = 0; k < FN; ++k) acc = fmaf(xrow[k], wx[k], acc);
#pragma unroll
    for (int k = 0; k < OD; ++k) acc = fmaf(arow[k], wa[k], acc);
    out[(size_t)n * OD + lane] = fmaxf(acc, 0.0f);
}

// ---------------------------------------------------------------------------
extern "C" void kernel_launch(void* const* d_in, const int* in_sizes, int n_in,
                              void* d_out, int out_size, void* d_ws, size_t ws_size,
                              hipStream_t stream) {
    const float* x    = (const float*)d_in[0];   // (50000, 64)
    const int*   ei   = (const int*)d_in[1];     // (2, 800000)
    const float* ea   = (const float*)d_in[2];   // (800000, 32)
    const float* u    = (const float*)d_in[3];   // (256, 32)
    const int*   bat  = (const int*)d_in[4];     // (50000,)
    const float* W1   = (const float*)d_in[5];   // (96, 64)
    const float* b1   = (const float*)d_in[6];   // (64,)
    const float* W2   = (const float*)d_in[7];   // (160, 64)
    const float* b2   = (const float*)d_in[8];   // (64,)
    float* out = (float*)d_out;                  // (50000, 64)

    // workspace layout
    char* ws = (char*)d_ws;
    auto alloc = [&](size_t bytes) {
        char* p = ws;
        ws += (bytes + 255) & ~size_t(255);
        return p;
    };
    unsigned short* xb = (unsigned short*)alloc((size_t)NN * FN * 2);      // 6.4 MB
    float* agg    = (float*)alloc((size_t)NN * OD * sizeof(float));        // 12.8 MB
    float* uW2b   = (float*)alloc((size_t)NG * OD * sizeof(float));
    int*   cnt    = (int*)alloc((size_t)NN * sizeof(int));
    int*   start  = (int*)alloc((size_t)(NN + 1) * sizeof(int));
    int*   cursor = (int*)alloc((size_t)NN * sizeof(int));
    int*   bsum   = (int*)alloc((size_t)NBLK * sizeof(int));
    int*   bscan  = (int*)alloc((size_t)NBLK * sizeof(int));
    int2*  bucket = (int2*)alloc((size_t)NE * sizeof(int2));               // 6.4 MB

    hipMemsetAsync(cnt, 0, (size_t)NN * sizeof(int), stream);

    // precomputes
    k_xcvt<<<dim3((NN * FN / 8 + 255) / 256), dim3(256), 0, stream>>>(x, (unsigned*)xb);
    k_uw2<<<dim3((NG * 64 + 255) / 256), dim3(256), 0, stream>>>(u, W2, b2, uW2b);

    // bucket edges by destination
    k_hist<<<dim3((NE + 255) / 256), dim3(256), 0, stream>>>(ei, cnt);
    k_scan1<<<dim3(NBLK), dim3(SCAN_B), 0, stream>>>(cnt, start, bsum);
    k_scan2<<<dim3(1), dim3(SCAN_B), 0, stream>>>(bsum, bscan);
    k_scan3<<<dim3(NBLK), dim3(SCAN_B), 0, stream>>>(start, bscan, cursor);
    k_scatter<<<dim3((NE + 255) / 256), dim3(256), 0, stream>>>(ei, cursor, bucket);

    // aggregate (MFMA, atomic-free)
    k_aggm<<<dim3((NN * 64 + 255) / 256), dim3(256), 0, stream>>>(bucket, ea, xb, W1, b1, start, agg);

    // node MLP
    k_node<<<dim3((NN * 64 + 255) / 256), dim3(256), 0, stream>>>(x, agg, bat, uW2b, W2, out);
}

// Round 4
// 169.601 us; speedup vs baseline: 1.6994x; 1.4255x over previous
//
#include <hip/hip_runtime.h>
#include <hip/hip_bf16.h>

typedef __attribute__((ext_vector_type(8))) short short8;
typedef __attribute__((ext_vector_type(4))) float f32x4;

// Problem constants (from reference)
constexpr int NN = 50000;   // nodes
constexpr int NE = 800000;  // edges
constexpr int FN = 64;      // node feat
constexpr int FE = 32;      // edge feat
constexpr int FG = 32;      // global feat
constexpr int OD = 64;      // out dim
constexpr int NG = 256;     // graphs

constexpr int SCAN_B = 256;
constexpr int NBLK = (NN + SCAN_B - 1) / SCAN_B;  // 196

constexpr int AGG_BLOCKS = 2048;                  // 8 blocks/CU -> full occupancy
constexpr int AGG_WAVES  = AGG_BLOCKS * 4;        // 8192 waves, ~6 nodes each
constexpr int NWIN       = NN / 16;               // 3125 node-windows (exact)
constexpr int NODE_BLOCKS = 512;
constexpr int NODE_WAVES  = NODE_BLOCKS * 4;      // 2048 waves, ~1.5 windows each

static __device__ __forceinline__ unsigned pack_bf16(float a, float b) {
    __hip_bfloat162 h = __float22bfloat162_rn(float2{a, b});
    return *reinterpret_cast<unsigned*>(&h);
}

// ---------------------------------------------------------------------------
// x (f32) -> x_bf16 table (50000 x 64)
// ---------------------------------------------------------------------------
__global__ __launch_bounds__(256) void k_xcvt(const float* __restrict__ x,
                                              unsigned* __restrict__ xb32) {
    const int i = blockIdx.x * 256 + threadIdx.x;  // per 8 elements
    if (i >= NN * FN / 8) return;
    const float4* p = (const float4*)(x + (size_t)i * 8);
    float4 f0 = p[0], f1 = p[1];
    uint4 o;
    o.x = pack_bf16(f0.x, f0.y);
    o.y = pack_bf16(f0.z, f0.w);
    o.z = pack_bf16(f1.x, f1.y);
    o.w = pack_bf16(f1.z, f1.w);
    ((uint4*)xb32)[i] = o;
}

// ---------------------------------------------------------------------------
// uW2b[g][j] = b2[j] + sum_k u[g][k] * W2[(128+k)][j]   (exact f32)
// ---------------------------------------------------------------------------
__global__ __launch_bounds__(256) void k_uw2(const float* __restrict__ u,
                                             const float* __restrict__ W2,
                                             const float* __restrict__ b2,
                                             float* __restrict__ uW2b) {
    const int lane = threadIdx.x & 63;
    float wcol[FG];
#pragma unroll
    for (int k = 0; k < FG; ++k) wcol[k] = W2[(FN + OD + k) * OD + lane];
    const float bias = b2[lane];

    int g = (blockIdx.x * blockDim.x + threadIdx.x) >> 6;
    g = __builtin_amdgcn_readfirstlane(g);
    if (g >= NG) return;

    const float* __restrict__ urow = u + (size_t)g * FG;
    float acc = bias;
#pragma unroll
    for (int k = 0; k < FG; ++k) acc = fmaf(urow[k], wcol[k], acc);
    uW2b[(size_t)g * OD + lane] = acc;
}

// ---------------------------------------------------------------------------
// Bucketing: histogram of dst (int atomics), 3-step scan, scatter {src,e}.
// ---------------------------------------------------------------------------
__global__ __launch_bounds__(256) void k_hist(const int* __restrict__ ei,
                                              int* __restrict__ cnt) {
    const int e = blockIdx.x * blockDim.x + threadIdx.x;
    if (e < NE) atomicAdd(&cnt[ei[e]], 1);
}

__global__ __launch_bounds__(SCAN_B) void k_scan1(const int* __restrict__ cnt,
                                                  int* __restrict__ start,
                                                  int* __restrict__ bsum) {
    __shared__ int lds[SCAN_B];
    const int i = blockIdx.x * SCAN_B + threadIdx.x;
    const int v = (i < NN) ? cnt[i] : 0;
    lds[threadIdx.x] = v;
    __syncthreads();
#pragma unroll
    for (int off = 1; off < SCAN_B; off <<= 1) {
        int t = (threadIdx.x >= off) ? lds[threadIdx.x - off] : 0;
        __syncthreads();
        lds[threadIdx.x] += t;
        __syncthreads();
    }
    const int incl = lds[threadIdx.x];
    if (i < NN) start[i] = incl - v;  // exclusive within block
    if (threadIdx.x == SCAN_B - 1) bsum[blockIdx.x] = incl;
}

__global__ __launch_bounds__(SCAN_B) void k_scan2(const int* __restrict__ bsum,
                                                  int* __restrict__ bscan) {
    __shared__ int lds[SCAN_B];
    const int i = threadIdx.x;
    const int v = (i < NBLK) ? bsum[i] : 0;
    lds[i] = v;
    __syncthreads();
#pragma unroll
    for (int off = 1; off < SCAN_B; off <<= 1) {
        int t = (i >= off) ? lds[i - off] : 0;
        __syncthreads();
        lds[i] += t;
        __syncthreads();
    }
    if (i < NBLK) bscan[i] = lds[i] - v;  // exclusive block offsets
}

__global__ __launch_bounds__(SCAN_B) void k_scan3(int* __restrict__ start,
                                                  const int* __restrict__ bscan,
                                                  int* __restrict__ cursor) {
    const int i = blockIdx.x * SCAN_B + threadIdx.x;
    if (i < NN) {
        const int s = start[i] + bscan[blockIdx.x];
        start[i] = s;
        cursor[i] = s;
    }
    if (i == 0) start[NN] = NE;
}

__global__ __launch_bounds__(256) void k_scatter(const int* __restrict__ ei,
                                                 int* __restrict__ cursor,
                                                 int2* __restrict__ bucket) {
    const int e = blockIdx.x * blockDim.x + threadIdx.x;
    if (e < NE) {
        const int dst = ei[e];
        const int src = ei[NE + e];
        const int pos = atomicAdd(&cursor[dst], 1);
        bucket[pos] = make_int2(src, e);
    }
}

// ---------------------------------------------------------------------------
// Aggregation via MFMA, PERSISTENT waves (~6 nodes/wave amortize W1 setup).
//   msg[r][j] = relu( [x_bf16[src_r] | ea_r] @ W1 + b1 ),  r = edge in window
//   aggb[n][j] = bf16( sum over windows, rows masked to valid count )
// Fragment layouts (mfma_f32_16x16x32_bf16):
//   A: row = lane&15, k = 8*(lane>>4)+i ; B: col = lane&15, same k
//   C: col = lane&15, row = (lane>>4)*4 + q   [measured m89]
// ---------------------------------------------------------------------------
__global__ __launch_bounds__(256) void k_aggm(const int2* __restrict__ bucket,
                                              const float* __restrict__ ea,
                                              const unsigned short* __restrict__ xb,
                                              const float* __restrict__ W1,
                                              const float* __restrict__ b1,
                                              const int* __restrict__ start,
                                              unsigned short* __restrict__ aggb) {
    const int l = threadIdx.x & 63;
    const int g = l >> 4;   // k-group (A/B), row-group (C)
    const int c = l & 15;   // A row / B,C col-in-block

    // W1 B-fragments: wf[t][b] covers k = 32t.., cols 16b..16b+15
    short8 wf[3][4];
#pragma unroll
    for (int t = 0; t < 3; ++t)
#pragma unroll
        for (int b = 0; b < 4; ++b)
#pragma unroll
            for (int i = 0; i < 8; i += 2) {
                const int k = 32 * t + 8 * g + i;
                const unsigned p = pack_bf16(W1[k * OD + (c + 16 * b)],
                                             W1[(k + 1) * OD + (c + 16 * b)]);
                ((unsigned*)&wf[t][b])[i / 2] = p;
            }
    float bias[4];
#pragma unroll
    for (int b = 0; b < 4; ++b) bias[b] = b1[c + 16 * b];

    int wv = (blockIdx.x * blockDim.x + threadIdx.x) >> 6;
    wv = __builtin_amdgcn_readfirstlane(wv);

    for (int n = wv; n < NN; n += AGG_WAVES) {
        const int s0 = start[n];
        const int s1 = start[n + 1];

        f32x4 wsum[4] = {f32x4{0,0,0,0}, f32x4{0,0,0,0},
                         f32x4{0,0,0,0}, f32x4{0,0,0,0}};

        for (int w0 = s0; w0 < s1; w0 += 16) {
            const int valid = s1 - w0;  // rows >= valid are clamped duplicates
            int idx = w0 + c;
            if (idx >= s1) idx = s1 - 1;
            const int2 se = bucket[idx];  // {src, e}

            // A fragments: chunks 0,1 = x_bf16[src], chunk 2 = cvt(ea[e])
            short8 a0, a1, a2;
            {
                const uint4* xr = (const uint4*)(xb + (size_t)se.x * FN);
                uint4 q0 = xr[g];      // k = 8g..8g+7
                uint4 q1 = xr[4 + g];  // k = 32+8g..
                a0 = *(short8*)&q0;
                a1 = *(short8*)&q1;
            }
            {
                const float4* er = (const float4*)(ea + (size_t)se.y * FE);
                float4 e0 = er[2 * g], e1 = er[2 * g + 1];
                uint4 q2;
                q2.x = pack_bf16(e0.x, e0.y);
                q2.y = pack_bf16(e0.z, e0.w);
                q2.z = pack_bf16(e1.x, e1.y);
                q2.w = pack_bf16(e1.z, e1.w);
                a2 = *(short8*)&q2;
            }

#pragma unroll
            for (int b = 0; b < 4; ++b) {
                f32x4 acc = {0.f, 0.f, 0.f, 0.f};
                acc = __builtin_amdgcn_mfma_f32_16x16x32_bf16(a0, wf[0][b], acc, 0, 0, 0);
                acc = __builtin_amdgcn_mfma_f32_16x16x32_bf16(a1, wf[1][b], acc, 0, 0, 0);
                acc = __builtin_amdgcn_mfma_f32_16x16x32_bf16(a2, wf[2][b], acc, 0, 0, 0);
#pragma unroll
                for (int q = 0; q < 4; ++q) {
                    const int row = g * 4 + q;
                    float v = fmaxf(acc[q] + bias[b], 0.0f);
                    wsum[b][q] += (row < valid) ? v : 0.0f;
                }
            }
        }

        // reduce rows: in-lane over q, cross-lane over row-groups (^16, ^32)
        float s0v = wsum[0][0] + wsum[0][1] + wsum[0][2] + wsum[0][3];
        float s1v = wsum[1][0] + wsum[1][1] + wsum[1][2] + wsum[1][3];
        float s2v = wsum[2][0] + wsum[2][1] + wsum[2][2] + wsum[2][3];
        float s3v = wsum[3][0] + wsum[3][1] + wsum[3][2] + wsum[3][3];
        s0v += __shfl_xor(s0v, 16); s0v += __shfl_xor(s0v, 32);
        s1v += __shfl_xor(s1v, 16); s1v += __shfl_xor(s1v, 32);
        s2v += __shfl_xor(s2v, 16); s2v += __shfl_xor(s2v, 32);
        s3v += __shfl_xor(s3v, 16); s3v += __shfl_xor(s3v, 32);

        float v = s0v;
        v = (g == 1) ? s1v : v;
        v = (g == 2) ? s2v : v;
        v = (g == 3) ? s3v : v;
        __hip_bfloat16 hb = __float2bfloat16(v);
        aggb[(size_t)n * OD + c + 16 * g] = *reinterpret_cast<unsigned short*>(&hb);
    }
}

// ---------------------------------------------------------------------------
// Node MLP via MFMA: out = relu([x_bf16 | agg_bf16] @ W2[0:128] + uW2b[batch])
// 16 nodes per window; A rows = consecutive nodes (coalesced); same layouts.
// ---------------------------------------------------------------------------
__global__ __launch_bounds__(256) void k_nodem(const unsigned short* __restrict__ xb,
                                               const unsigned short* __restrict__ aggb,
                                               const int* __restrict__ bat,
                                               const float* __restrict__ uW2b,
                                               const float* __restrict__ W2,
                                               float* __restrict__ out) {
    const int l = threadIdx.x & 63;
    const int g = l >> 4;
    const int c = l & 15;

    // W2 B-fragments: wf[t][b] covers k = 32t.. (rows 0..127 = [x | agg])
    short8 wf[4][4];
#pragma unroll
    for (int t = 0; t < 4; ++t)
#pragma unroll
        for (int b = 0; b < 4; ++b)
#pragma unroll
            for (int i = 0; i < 8; i += 2) {
                const int k = 32 * t + 8 * g + i;
                const unsigned p = pack_bf16(W2[k * OD + (c + 16 * b)],
                                             W2[(k + 1) * OD + (c + 16 * b)]);
                ((unsigned*)&wf[t][b])[i / 2] = p;
            }

    int wv = (blockIdx.x * blockDim.x + threadIdx.x) >> 6;
    wv = __builtin_amdgcn_readfirstlane(wv);

    for (int w = wv; w < NWIN; w += NODE_WAVES) {
        const int n0 = w * 16;

        // A fragments: row = node n0+c; k 0..63 from xb, 64..127 from aggb
        const uint4* xr = (const uint4*)(xb + (size_t)(n0 + c) * FN);
        const uint4* ar = (const uint4*)(aggb + (size_t)(n0 + c) * OD);
        uint4 qx0 = xr[g], qx1 = xr[4 + g];
        uint4 qa0 = ar[g], qa1 = ar[4 + g];
        short8 a0 = *(short8*)&qx0, a1 = *(short8*)&qx1;
        short8 a2 = *(short8*)&qa0, a3 = *(short8*)&qa1;

        int bq[4];
#pragma unroll
        for (int q = 0; q < 4; ++q) bq[q] = bat[n0 + g * 4 + q];

#pragma unroll
        for (int b = 0; b < 4; ++b) {
            f32x4 acc = {0.f, 0.f, 0.f, 0.f};
            acc = __builtin_amdgcn_mfma_f32_16x16x32_bf16(a0, wf[0][b], acc, 0, 0, 0);
            acc = __builtin_amdgcn_mfma_f32_16x16x32_bf16(a1, wf[1][b], acc, 0, 0, 0);
            acc = __builtin_amdgcn_mfma_f32_16x16x32_bf16(a2, wf[2][b], acc, 0, 0, 0);
            acc = __builtin_amdgcn_mfma_f32_16x16x32_bf16(a3, wf[3][b], acc, 0, 0, 0);
#pragma unroll
            for (int q = 0; q < 4; ++q) {
                const int n = n0 + g * 4 + q;
                const float val = acc[q] + uW2b[(size_t)bq[q] * OD + c + 16 * b];
                out[(size_t)n * OD + c + 16 * b] = fmaxf(val, 0.0f);
            }
        }
    }
}

// ---------------------------------------------------------------------------
extern "C" void kernel_launch(void* const* d_in, const int* in_sizes, int n_in,
                              void* d_out, int out_size, void* d_ws, size_t ws_size,
                              hipStream_t stream) {
    const float* x    = (const float*)d_in[0];   // (50000, 64)
    const int*   ei   = (const int*)d_in[1];     // (2, 800000)
    const float* ea   = (const float*)d_in[2];   // (800000, 32)
    const float* u    = (const float*)d_in[3];   // (256, 32)
    const int*   bat  = (const int*)d_in[4];     // (50000,)
    const float* W1   = (const float*)d_in[5];   // (96, 64)
    const float* b1   = (const float*)d_in[6];   // (64,)
    const float* W2   = (const float*)d_in[7];   // (160, 64)
    const float* b2   = (const float*)d_in[8];   // (64,)
    float* out = (float*)d_out;                  // (50000, 64)

    // workspace layout
    char* ws = (char*)d_ws;
    auto alloc = [&](size_t bytes) {
        char* p = ws;
        ws += (bytes + 255) & ~size_t(255);
        return p;
    };
    unsigned short* xb   = (unsigned short*)alloc((size_t)NN * FN * 2);   // 6.4 MB
    unsigned short* aggb = (unsigned short*)alloc((size_t)NN * OD * 2);   // 6.4 MB
    float* uW2b   = (float*)alloc((size_t)NG * OD * sizeof(float));
    int*   cnt    = (int*)alloc((size_t)NN * sizeof(int));
    int*   start  = (int*)alloc((size_t)(NN + 1) * sizeof(int));
    int*   cursor = (int*)alloc((size_t)NN * sizeof(int));
    int*   bsum   = (int*)alloc((size_t)NBLK * sizeof(int));
    int*   bscan  = (int*)alloc((size_t)NBLK * sizeof(int));
    int2*  bucket = (int2*)alloc((size_t)NE * sizeof(int2));              // 6.4 MB

    hipMemsetAsync(cnt, 0, (size_t)NN * sizeof(int), stream);

    // precomputes
    k_xcvt<<<dim3((NN * FN / 8 + 255) / 256), dim3(256), 0, stream>>>(x, (unsigned*)xb);
    k_uw2<<<dim3((NG * 64 + 255) / 256), dim3(256), 0, stream>>>(u, W2, b2, uW2b);

    // bucket edges by destination
    k_hist<<<dim3((NE + 255) / 256), dim3(256), 0, stream>>>(ei, cnt);
    k_scan1<<<dim3(NBLK), dim3(SCAN_B), 0, stream>>>(cnt, start, bsum);
    k_scan2<<<dim3(1), dim3(SCAN_B), 0, stream>>>(bsum, bscan);
    k_scan3<<<dim3(NBLK), dim3(SCAN_B), 0, stream>>>(start, bscan, cursor);
    k_scatter<<<dim3((NE + 255) / 256), dim3(256), 0, stream>>>(ei, cursor, bucket);

    // aggregate (MFMA, persistent, atomic-free)
    k_aggm<<<dim3(AGG_BLOCKS), dim3(256), 0, stream>>>(bucket, ea, xb, W1, b1, start, aggb);

    // node MLP (MFMA)
    k_nodem<<<dim3(NODE_BLOCKS), dim3(256), 0, stream>>>(xb, aggb, bat, uW2b, W2, out);
}